// Round 1
// baseline (1111.496 us; speedup 1.0000x reference)
//
#include <hip/hip_runtime.h>

constexpr int NN = 50000;   // nodes
constexpr int NE = 800000;  // edges
constexpr int H  = 64;      // hidden
constexpr int NG = 64;      // graphs

// ---------------- degree / norm ----------------
__global__ void k_deg_init(float* __restrict__ deg) {
    int i = blockIdx.x * blockDim.x + threadIdx.x;
    if (i < NN) deg[i] = 1.0f;   // self-loop contributes 1
}

__global__ void k_deg_acc(const int* __restrict__ dst, float* __restrict__ deg) {
    int e = blockIdx.x * blockDim.x + threadIdx.x;
    if (e < NE) atomicAdd(&deg[dst[e]], 1.0f);
}

__global__ void k_dinv(float* __restrict__ deg) {
    int i = blockIdx.x * blockDim.x + threadIdx.x;
    if (i < NN) deg[i] = rsqrtf(deg[i]);   // deg >= 1 always (self-loops)
}

__global__ void k_norm(const int* __restrict__ src, const int* __restrict__ dst,
                       const float* __restrict__ dinv, float* __restrict__ norm) {
    int e = blockIdx.x * blockDim.x + threadIdx.x;
    if (e < NE) norm[e] = dinv[src[e]] * dinv[dst[e]];
}

// ---------------- dense per-node GEMM: t = act(h) @ W ----------------
// block = 256 threads = 4 rows x 64 channels; W (K x 64) staged in LDS.
template <int K, bool RELU>
__global__ void k_gemm(const float* __restrict__ h, const float* __restrict__ W,
                       float* __restrict__ t) {
    __shared__ float Wl[K * H];
    for (int i = threadIdx.x; i < K * H; i += blockDim.x) Wl[i] = W[i];
    __syncthreads();
    int idx = blockIdx.x * blockDim.x + threadIdx.x;
    int r = idx >> 6, c = idx & 63;
    if (r >= NN) return;
    const float* hr = h + (long long)r * K;
    float acc = 0.0f;
#pragma unroll
    for (int k = 0; k < K; ++k) {
        float v = hr[k];
        if (RELU) v = fmaxf(v, 0.0f);
        acc = fmaf(v, Wl[k * H + c], acc);
    }
    t[(long long)r * H + c] = acc;
}

// ---------------- conv epilogue init: out = b + t * dinv^2 (self-loop) ----------------
__global__ void k_init_out(const float* __restrict__ t, const float* __restrict__ dinv,
                           const float* __restrict__ b, float* __restrict__ out) {
    int idx = blockIdx.x * blockDim.x + threadIdx.x;
    if (idx >= NN * H) return;
    int r = idx >> 6, c = idx & 63;
    float d = dinv[r];
    out[idx] = b[c] + t[idx] * d * d;
}

// ---------------- edge scatter: out[dst] += t[src] * norm ----------------
// one lane per (edge, channel): 64 lanes cover one edge's row (256 B coalesced)
__global__ void k_scatter(const float* __restrict__ t, const int* __restrict__ src,
                          const int* __restrict__ dst, const float* __restrict__ norm,
                          float* __restrict__ out) {
    long long idx = (long long)blockIdx.x * blockDim.x + threadIdx.x;
    int e = (int)(idx >> 6), c = (int)(idx & 63);
    if (e >= NE) return;
    int s = src[e], d = dst[e];
    float v = t[(long long)s * H + c] * norm[e];
    atomicAdd(&out[(long long)d * H + c], v);
}

// ---------------- pooling ----------------
__global__ void k_pool_zero(float* __restrict__ sums, float* __restrict__ cnt) {
    int i = blockIdx.x * blockDim.x + threadIdx.x;
    if (i < NG * H) sums[i] = 0.0f;
    if (i < NG) cnt[i] = 0.0f;
}

__global__ void k_pool(const float* __restrict__ h, const int* __restrict__ batch,
                       float* __restrict__ sums, float* __restrict__ cnt) {
    int idx = blockIdx.x * blockDim.x + threadIdx.x;
    if (idx >= NN * H) return;
    int r = idx >> 6, c = idx & 63;
    int g = batch[r];
    atomicAdd(&sums[g * H + c], h[idx]);
    if (c == 0) atomicAdd(&cnt[g], 1.0f);
}

// ---------------- head: g = sums/cnt; p = g@Wpre+bpre; out = p@Wlin+blin ----------------
__global__ void k_head(const float* __restrict__ sums, const float* __restrict__ cnt,
                       const float* __restrict__ Wpre, const float* __restrict__ bpre,
                       const float* __restrict__ Wlin, const float* __restrict__ blin,
                       float* __restrict__ out) {
    __shared__ float g[NG * H];    // 16 KB
    __shared__ float p[NG * 32];   // 8 KB
    int tid = threadIdx.x;
    for (int i = tid; i < NG * H; i += blockDim.x) {
        int gi = i >> 6;
        g[i] = sums[i] / fmaxf(cnt[gi], 1.0f);
    }
    __syncthreads();
    for (int i = tid; i < NG * 32; i += blockDim.x) {
        int gi = i >> 5, j = i & 31;
        float acc = bpre[j];
        for (int k = 0; k < H; ++k) acc = fmaf(g[gi * H + k], Wpre[k * 32 + j], acc);
        p[i] = acc;
    }
    __syncthreads();
    for (int i = tid; i < NG * 4; i += blockDim.x) {
        int gi = i >> 2, o = i & 3;
        float acc = blin[o];
        for (int j = 0; j < 32; ++j) acc = fmaf(p[gi * 32 + j], Wlin[j * 4 + o], acc);
        out[i] = acc;
    }
}

extern "C" void kernel_launch(void* const* d_in, const int* in_sizes, int n_in,
                              void* d_out, int out_size, void* d_ws, size_t ws_size,
                              hipStream_t stream) {
    const float* x     = (const float*)d_in[0];    // [NN,4]
    const int*   ei    = (const int*)d_in[1];      // [2,NE] flat: src then dst
    const int*   batch = (const int*)d_in[2];      // [NN]
    const float* W1    = (const float*)d_in[3];
    const float* b1    = (const float*)d_in[4];
    const float* W2    = (const float*)d_in[5];
    const float* b2    = (const float*)d_in[6];
    const float* W3    = (const float*)d_in[7];
    const float* b3    = (const float*)d_in[8];
    const float* Wpre  = (const float*)d_in[9];
    const float* bpre  = (const float*)d_in[10];
    const float* Wlin  = (const float*)d_in[11];
    const float* blin  = (const float*)d_in[12];
    float* out = (float*)d_out;

    const int* src = ei;
    const int* dst = ei + NE;

    // workspace layout (float offsets)
    float* ws   = (float*)d_ws;
    float* deg  = ws;                        // NN (becomes dinv in place)
    float* norm = ws + 51200;                // NE
    float* tbuf = ws + 51200 + NE;           // NN*H
    float* hA   = tbuf + (long long)NN * H;  // NN*H
    float* hB   = hA + (long long)NN * H;    // NN*H
    float* sums = hB + (long long)NN * H;    // NG*H
    float* cnt  = sums + NG * H;             // NG

    const int B = 256;
    const int gN   = (NN + B - 1) / B;           // per-node
    const int gE   = (NE + B - 1) / B;           // per-edge
    const int gNH  = (NN * H + B - 1) / B;       // per-(node,channel)
    const int gEH  = (int)(((long long)NE * H + B - 1) / B);  // per-(edge,channel)

    // norm precompute
    k_deg_init<<<gN, B, 0, stream>>>(deg);
    k_deg_acc<<<gE, B, 0, stream>>>(dst, deg);
    k_dinv<<<gN, B, 0, stream>>>(deg);
    k_norm<<<gE, B, 0, stream>>>(src, dst, deg, norm);

    // conv1: x(N,4) -> hA
    k_gemm<4, false><<<gNH, B, 0, stream>>>(x, W1, tbuf);
    k_init_out<<<gNH, B, 0, stream>>>(tbuf, deg, b1, hA);
    k_scatter<<<gEH, B, 0, stream>>>(tbuf, src, dst, norm, hA);

    // conv2: relu(hA) -> hB
    k_gemm<H, true><<<gNH, B, 0, stream>>>(hA, W2, tbuf);
    k_init_out<<<gNH, B, 0, stream>>>(tbuf, deg, b2, hB);
    k_scatter<<<gEH, B, 0, stream>>>(tbuf, src, dst, norm, hB);

    // conv3: relu(hB) -> hA
    k_gemm<H, true><<<gNH, B, 0, stream>>>(hB, W3, tbuf);
    k_init_out<<<gNH, B, 0, stream>>>(tbuf, deg, b3, hA);
    k_scatter<<<gEH, B, 0, stream>>>(tbuf, src, dst, norm, hA);

    // mean pool + head
    k_pool_zero<<<(NG * H + B - 1) / B, B, 0, stream>>>(sums, cnt);
    k_pool<<<gNH, B, 0, stream>>>(hA, batch, sums, cnt);
    k_head<<<1, B, 0, stream>>>(sums, cnt, Wpre, bpre, Wlin, blin, out);
}

// Round 2
// 477.815 us; speedup vs baseline: 2.3262x; 2.3262x over previous
//
#include <hip/hip_runtime.h>

constexpr int NN = 50000;   // nodes
constexpr int NE = 800000;  // edges
constexpr int H  = 64;      // hidden
constexpr int NG = 64;      // graphs

// ---------------- CSR build ----------------
__global__ void k_degi(const int* __restrict__ dst, int* __restrict__ degi) {
    int e = blockIdx.x * blockDim.x + threadIdx.x;
    if (e < NE) atomicAdd(&degi[dst[e]], 1);
}

// single-block exclusive scan over degi[NN] -> rowptr[NN+1]
__global__ void k_scan(const int* __restrict__ degi, int* __restrict__ rowptr) {
    constexpr int CH = (NN + 1023) / 1024;  // 49
    int tid = threadIdx.x;
    int beg = tid * CH, end = min(NN, beg + CH);
    int s = 0;
    for (int i = beg; i < end; ++i) s += degi[i];
    // wave-level inclusive scan
    int lane = tid & 63, w = tid >> 6;
    int v = s;
    for (int off = 1; off < 64; off <<= 1) {
        int u = __shfl_up(v, off);
        if (lane >= off) v += u;
    }
    __shared__ int wsum[16];
    if (lane == 63) wsum[w] = v;
    __syncthreads();
    if (tid == 0) {
        int a = 0;
        for (int i = 0; i < 16; ++i) { int t = wsum[i]; wsum[i] = a; a += t; }
    }
    __syncthreads();
    int run = v - s + wsum[w];   // exclusive prefix of this thread's chunk
    for (int i = beg; i < end; ++i) { rowptr[i] = run; run += degi[i]; }
    if (tid == 1023) rowptr[NN] = run;   // empty chunk => run == NE
}

__global__ void k_dinv(const int* __restrict__ degi, float* __restrict__ dinv) {
    int i = blockIdx.x * blockDim.x + threadIdx.x;
    if (i < NN) dinv[i] = rsqrtf((float)(degi[i] + 1));   // +1 self-loop
}

__global__ void k_fill(const int* __restrict__ src, const int* __restrict__ dst,
                       const int* __restrict__ rowptr, const float* __restrict__ dinv,
                       int* __restrict__ fillc, int* __restrict__ csr_src,
                       float* __restrict__ csr_w) {
    int e = blockIdx.x * blockDim.x + threadIdx.x;
    if (e >= NE) return;
    int s = src[e], d = dst[e];
    int pos = rowptr[d] + atomicAdd(&fillc[d], 1);
    csr_src[pos] = s;
    csr_w[pos] = dinv[s] * dinv[d];
}

// ---------------- dense per-node GEMM: t = act(h) @ W ----------------
template <int K, bool RELU>
__global__ void k_gemm(const float* __restrict__ h, const float* __restrict__ W,
                       float* __restrict__ t) {
    __shared__ float Wl[K * H];
    for (int i = threadIdx.x; i < K * H; i += blockDim.x) Wl[i] = W[i];
    __syncthreads();
    int idx = blockIdx.x * blockDim.x + threadIdx.x;
    int r = idx >> 6, c = idx & 63;
    if (r >= NN) return;
    const float* hr = h + (long long)r * K;
    float acc = 0.0f;
#pragma unroll
    for (int k = 0; k < K; ++k) {
        float v = hr[k];
        if (RELU) v = fmaxf(v, 0.0f);
        acc = fmaf(v, Wl[k * H + c], acc);
    }
    t[(long long)r * H + c] = acc;
}

// ---------------- pull conv: out[d] = b + t[d]*dinv[d]^2 + sum_in t[s]*w ----------------
// one wave (64 lanes = 64 channels) per destination node
__global__ void k_conv(const float* __restrict__ t, const int* __restrict__ rowptr,
                       const int* __restrict__ csr_src, const float* __restrict__ csr_w,
                       const float* __restrict__ dinv, const float* __restrict__ b,
                       float* __restrict__ out) {
    int wid = (blockIdx.x * blockDim.x + threadIdx.x) >> 6;
    int c = threadIdx.x & 63;
    if (wid >= NN) return;
    float dd = dinv[wid];
    float acc = b[c] + t[(long long)wid * H + c] * dd * dd;
    int beg = rowptr[wid], end = rowptr[wid + 1];
    for (int base = beg; base < end; base += 64) {
        int k = base + c;
        int s = 0; float w = 0.0f;
        if (k < end) { s = csr_src[k]; w = csr_w[k]; }
        int n = min(64, end - base);
        for (int j = 0; j < n; ++j) {
            int ss = __shfl(s, j);
            float ww = __shfl(w, j);
            acc = fmaf(t[(long long)ss * H + c], ww, acc);
        }
    }
    out[(long long)wid * H + c] = acc;
}

// ---------------- pooling: run-length segmented reduction (batch is sorted) ----------------
constexpr int POOL_WAVES = 512;
constexpr int POOL_STRIP = (NN + POOL_WAVES - 1) / POOL_WAVES;  // 98

__global__ void k_pool(const float* __restrict__ h, const int* __restrict__ batch,
                       float* __restrict__ sums, float* __restrict__ cnt) {
    int wid = (blockIdx.x * blockDim.x + threadIdx.x) >> 6;
    int c = threadIdx.x & 63;
    int beg = wid * POOL_STRIP, end = min(NN, beg + POOL_STRIP);
    if (beg >= end) return;
    int curg = batch[beg];
    float acc = 0.0f; int run = 0;
    for (int r = beg; r < end; ++r) {
        int g = batch[r];
        if (g != curg) {
            atomicAdd(&sums[curg * H + c], acc);
            if (c == 0) atomicAdd(&cnt[curg], (float)run);
            curg = g; acc = 0.0f; run = 0;
        }
        acc += h[(long long)r * H + c];
        ++run;
    }
    atomicAdd(&sums[curg * H + c], acc);
    if (c == 0) atomicAdd(&cnt[curg], (float)run);
}

// ---------------- head ----------------
__global__ void k_head(const float* __restrict__ sums, const float* __restrict__ cnt,
                       const float* __restrict__ Wpre, const float* __restrict__ bpre,
                       const float* __restrict__ Wlin, const float* __restrict__ blin,
                       float* __restrict__ out) {
    __shared__ float g[NG * H];
    __shared__ float p[NG * 32];
    int tid = threadIdx.x;
    for (int i = tid; i < NG * H; i += blockDim.x) {
        int gi = i >> 6;
        g[i] = sums[i] / fmaxf(cnt[gi], 1.0f);
    }
    __syncthreads();
    for (int i = tid; i < NG * 32; i += blockDim.x) {
        int gi = i >> 5, j = i & 31;
        float acc = bpre[j];
        for (int k = 0; k < H; ++k) acc = fmaf(g[gi * H + k], Wpre[k * 32 + j], acc);
        p[i] = acc;
    }
    __syncthreads();
    for (int i = tid; i < NG * 4; i += blockDim.x) {
        int gi = i >> 2, o = i & 3;
        float acc = blin[o];
        for (int j = 0; j < 32; ++j) acc = fmaf(p[gi * 32 + j], Wlin[j * 4 + o], acc);
        out[i] = acc;
    }
}

extern "C" void kernel_launch(void* const* d_in, const int* in_sizes, int n_in,
                              void* d_out, int out_size, void* d_ws, size_t ws_size,
                              hipStream_t stream) {
    const float* x     = (const float*)d_in[0];
    const int*   ei    = (const int*)d_in[1];
    const int*   batch = (const int*)d_in[2];
    const float* W1    = (const float*)d_in[3];
    const float* b1    = (const float*)d_in[4];
    const float* W2    = (const float*)d_in[5];
    const float* b2    = (const float*)d_in[6];
    const float* W3    = (const float*)d_in[7];
    const float* b3    = (const float*)d_in[8];
    const float* Wpre  = (const float*)d_in[9];
    const float* bpre  = (const float*)d_in[10];
    const float* Wlin  = (const float*)d_in[11];
    const float* blin  = (const float*)d_in[12];
    float* out = (float*)d_out;

    const int* src = ei;
    const int* dst = ei + NE;

    // workspace layout: [zeroed region: degi | fillc | sums | cnt] then the rest
    int*   degi   = (int*)d_ws;            // NN
    int*   fillc  = degi + NN;             // NN
    float* sums   = (float*)(fillc + NN);  // NG*H
    float* cnt    = sums + NG * H;         // NG
    int*   rowptr = (int*)(cnt + NG);      // NN+1
    int*   csr_s  = rowptr + NN + 1;       // NE
    float* csr_w  = (float*)(csr_s + NE);  // NE
    float* dinv   = csr_w + NE;            // NN
    float* tbuf   = dinv + NN;             // NN*H
    float* hA     = tbuf + (long long)NN * H;
    float* hB     = hA + (long long)NN * H;

    const int B = 256;
    const int gN  = (NN + B - 1) / B;
    const int gE  = (NE + B - 1) / B;
    const int gNH = (NN * H + B - 1) / B;   // one wave per node

    // zero degi, fillc, sums, cnt in one shot
    size_t zbytes = (size_t)(NN + NN + NG * H + NG) * 4;
    hipMemsetAsync(d_ws, 0, zbytes, stream);

    // CSR + norm
    k_degi<<<gE, B, 0, stream>>>(dst, degi);
    k_scan<<<1, 1024, 0, stream>>>(degi, rowptr);
    k_dinv<<<gN, B, 0, stream>>>(degi, dinv);
    k_fill<<<gE, B, 0, stream>>>(src, dst, rowptr, dinv, fillc, csr_s, csr_w);

    // conv1
    k_gemm<4, false><<<gNH, B, 0, stream>>>(x, W1, tbuf);
    k_conv<<<gNH, B, 0, stream>>>(tbuf, rowptr, csr_s, csr_w, dinv, b1, hA);
    // conv2
    k_gemm<H, true><<<gNH, B, 0, stream>>>(hA, W2, tbuf);
    k_conv<<<gNH, B, 0, stream>>>(tbuf, rowptr, csr_s, csr_w, dinv, b2, hB);
    // conv3
    k_gemm<H, true><<<gNH, B, 0, stream>>>(hB, W3, tbuf);
    k_conv<<<gNH, B, 0, stream>>>(tbuf, rowptr, csr_s, csr_w, dinv, b3, hA);

    // pool + head
    k_pool<<<POOL_WAVES / 4, B, 0, stream>>>(hA, batch, sums, cnt);
    k_head<<<1, B, 0, stream>>>(sums, cnt, Wpre, bpre, Wlin, blin, out);
}

// Round 3
// 360.376 us; speedup vs baseline: 3.0843x; 1.3259x over previous
//
#include <hip/hip_runtime.h>

constexpr int NN = 50000;   // nodes
constexpr int NE = 800000;  // edges
constexpr int H  = 64;      // hidden
constexpr int NG = 64;      // graphs

constexpr int SCAN_B  = 1024;
constexpr int SCAN_NB = (NN + SCAN_B - 1) / SCAN_B;  // 49

// ---------------- CSR build ----------------
__global__ void k_degi(const int* __restrict__ dst, int* __restrict__ degi) {
    int e = blockIdx.x * blockDim.x + threadIdx.x;
    if (e < NE) atomicAdd(&degi[dst[e]], 1);
}

// per-block local exclusive scan; bsum[b] = block total
__global__ void k_scanA(const int* __restrict__ degi, int* __restrict__ rowptr,
                        int* __restrict__ bsum) {
    int tid = threadIdx.x, b = blockIdx.x;
    int i = b * SCAN_B + tid;
    int d = (i < NN) ? degi[i] : 0;
    int lane = tid & 63, w = tid >> 6;
    int v = d;
    for (int off = 1; off < 64; off <<= 1) {
        int u = __shfl_up(v, off);
        if (lane >= off) v += u;
    }
    __shared__ int wt[16], wo[16], btot;
    if (lane == 63) wt[w] = v;
    __syncthreads();
    if (tid == 0) {
        int a = 0;
        for (int k = 0; k < 16; ++k) { wo[k] = a; a += wt[k]; }
        btot = a;
    }
    __syncthreads();
    if (i < NN) rowptr[i] = v - d + wo[w];
    if (tid == 0) bsum[b] = btot;
}

// single wave: bsum -> exclusive offsets (in place)
__global__ void k_scanB(int* __restrict__ bsum) {
    int lane = threadIdx.x;
    int v = (lane < SCAN_NB) ? bsum[lane] : 0;
    int s = v;
    for (int off = 1; off < 64; off <<= 1) {
        int u = __shfl_up(s, off);
        if (lane >= off) s += u;
    }
    if (lane < SCAN_NB) bsum[lane] = s - v;
}

// add block offsets; fuse dinv
__global__ void k_scanC(const int* __restrict__ bsum, int* __restrict__ rowptr,
                        const int* __restrict__ degi, float* __restrict__ dinv) {
    int i = blockIdx.x * SCAN_B + threadIdx.x;
    if (i < NN) {
        rowptr[i] += bsum[blockIdx.x];
        dinv[i] = rsqrtf((float)(degi[i] + 1));  // +1 self-loop
    }
    if (i == 0) rowptr[NN] = NE;
}

__global__ void k_fill(const int* __restrict__ src, const int* __restrict__ dst,
                       const int* __restrict__ rowptr, const float* __restrict__ dinv,
                       int* __restrict__ fillc, int* __restrict__ csr_src,
                       float* __restrict__ csr_w) {
    int e = blockIdx.x * blockDim.x + threadIdx.x;
    if (e >= NE) return;
    int s = src[e], d = dst[e];
    int pos = rowptr[d] + atomicAdd(&fillc[d], 1);
    csr_src[pos] = s;
    csr_w[pos] = dinv[s] * dinv[d];
}

// ---------------- dense per-node GEMM: t = act(h) @ W ----------------
template <int K, bool RELU>
__global__ void k_gemm(const float* __restrict__ h, const float* __restrict__ W,
                       float* __restrict__ t) {
    __shared__ float Wl[K * H];
    for (int i = threadIdx.x; i < K * H; i += blockDim.x) Wl[i] = W[i];
    __syncthreads();
    int idx = blockIdx.x * blockDim.x + threadIdx.x;
    int r = idx >> 6, c = idx & 63;
    if (r >= NN) return;
    const float4* h4 = (const float4*)(h + (long long)r * K);
    float acc = 0.0f;
#pragma unroll
    for (int k4 = 0; k4 < K / 4; ++k4) {
        float4 v = h4[k4];
        if (RELU) {
            v.x = fmaxf(v.x, 0.0f); v.y = fmaxf(v.y, 0.0f);
            v.z = fmaxf(v.z, 0.0f); v.w = fmaxf(v.w, 0.0f);
        }
        acc = fmaf(v.x, Wl[(4 * k4 + 0) * H + c], acc);
        acc = fmaf(v.y, Wl[(4 * k4 + 1) * H + c], acc);
        acc = fmaf(v.z, Wl[(4 * k4 + 2) * H + c], acc);
        acc = fmaf(v.w, Wl[(4 * k4 + 3) * H + c], acc);
    }
    t[(long long)r * H + c] = acc;
}

// ---------------- pull conv, float4 / 4-edges-per-pass ----------------
// wave = 1 dst node; lane = (g = lane>>4 edge group, l = lane&15 float4 slot)
__global__ void k_conv(const float* __restrict__ t, const int* __restrict__ rowptr,
                       const int* __restrict__ csr_src, const float* __restrict__ csr_w,
                       const float* __restrict__ dinv, const float* __restrict__ b,
                       float* __restrict__ out) {
    int wid = (blockIdx.x * blockDim.x + threadIdx.x) >> 6;
    int lane = threadIdx.x & 63;
    int l = lane & 15, g = lane >> 4;
    if (wid >= NN) return;
    float ax = 0.0f, ay = 0.0f, az = 0.0f, aw = 0.0f;
    int beg = rowptr[wid], end = rowptr[wid + 1];
    for (int base = beg; base < end; base += 64) {
        int k = base + lane;
        int s = 0; float w = 0.0f;
        if (k < end) { s = csr_src[k]; w = csr_w[k]; }
        int n = end - base; if (n > 64) n = 64;
        int iters = (n + 3) >> 2;
        for (int j = 0; j < iters; ++j) {
            int idx = 4 * j + g;
            int ss = __shfl(s, idx);
            float ww = __shfl(w, idx);
            const float4 v = *(const float4*)(t + (long long)ss * H + 4 * l);
            ax = fmaf(v.x, ww, ax);
            ay = fmaf(v.y, ww, ay);
            az = fmaf(v.z, ww, az);
            aw = fmaf(v.w, ww, aw);
        }
    }
    // reduce the 4 edge groups (lanes l, l+16, l+32, l+48)
    ax += __shfl_xor(ax, 16); ax += __shfl_xor(ax, 32);
    ay += __shfl_xor(ay, 16); ay += __shfl_xor(ay, 32);
    az += __shfl_xor(az, 16); az += __shfl_xor(az, 32);
    aw += __shfl_xor(aw, 16); aw += __shfl_xor(aw, 32);
    if (g == 0) {
        float dd = dinv[wid];
        float s2 = dd * dd;
        const float4 sv = *(const float4*)(t + (long long)wid * H + 4 * l);
        const float4 bv = *(const float4*)(b + 4 * l);
        float4 o;
        o.x = ax + bv.x + sv.x * s2;
        o.y = ay + bv.y + sv.y * s2;
        o.z = az + bv.z + sv.z * s2;
        o.w = aw + bv.w + sv.w * s2;
        *(float4*)(out + (long long)wid * H + 4 * l) = o;
    }
}

// ---------------- pooling: run-length segmented reduction (batch sorted) ----------------
constexpr int POOL_WAVES = 512;
constexpr int POOL_STRIP = (NN + POOL_WAVES - 1) / POOL_WAVES;  // 98

__global__ void k_pool(const float* __restrict__ h, const int* __restrict__ batch,
                       float* __restrict__ sums, float* __restrict__ cnt) {
    int wid = (blockIdx.x * blockDim.x + threadIdx.x) >> 6;
    int c = threadIdx.x & 63;
    int beg = wid * POOL_STRIP, end = min(NN, beg + POOL_STRIP);
    if (beg >= end) return;
    int curg = batch[beg];
    float acc = 0.0f; int run = 0;
    for (int r = beg; r < end; ++r) {
        int g = batch[r];
        if (g != curg) {
            atomicAdd(&sums[curg * H + c], acc);
            if (c == 0) atomicAdd(&cnt[curg], (float)run);
            curg = g; acc = 0.0f; run = 0;
        }
        acc += h[(long long)r * H + c];
        ++run;
    }
    atomicAdd(&sums[curg * H + c], acc);
    if (c == 0) atomicAdd(&cnt[curg], (float)run);
}

// ---------------- head ----------------
__global__ void k_head(const float* __restrict__ sums, const float* __restrict__ cnt,
                       const float* __restrict__ Wpre, const float* __restrict__ bpre,
                       const float* __restrict__ Wlin, const float* __restrict__ blin,
                       float* __restrict__ out) {
    __shared__ float g[NG * H];
    __shared__ float p[NG * 32];
    int tid = threadIdx.x;
    for (int i = tid; i < NG * H; i += blockDim.x) {
        int gi = i >> 6;
        g[i] = sums[i] / fmaxf(cnt[gi], 1.0f);
    }
    __syncthreads();
    for (int i = tid; i < NG * 32; i += blockDim.x) {
        int gi = i >> 5, j = i & 31;
        float acc = bpre[j];
        for (int k = 0; k < H; ++k) acc = fmaf(g[gi * H + k], Wpre[k * 32 + j], acc);
        p[i] = acc;
    }
    __syncthreads();
    for (int i = tid; i < NG * 4; i += blockDim.x) {
        int gi = i >> 2, o = i & 3;
        float acc = blin[o];
        for (int j = 0; j < 32; ++j) acc = fmaf(p[gi * 32 + j], Wlin[j * 4 + o], acc);
        out[i] = acc;
    }
}

extern "C" void kernel_launch(void* const* d_in, const int* in_sizes, int n_in,
                              void* d_out, int out_size, void* d_ws, size_t ws_size,
                              hipStream_t stream) {
    const float* x     = (const float*)d_in[0];
    const int*   ei    = (const int*)d_in[1];
    const int*   batch = (const int*)d_in[2];
    const float* W1    = (const float*)d_in[3];
    const float* b1    = (const float*)d_in[4];
    const float* W2    = (const float*)d_in[5];
    const float* b2    = (const float*)d_in[6];
    const float* W3    = (const float*)d_in[7];
    const float* b3    = (const float*)d_in[8];
    const float* Wpre  = (const float*)d_in[9];
    const float* bpre  = (const float*)d_in[10];
    const float* Wlin  = (const float*)d_in[11];
    const float* blin  = (const float*)d_in[12];
    float* out = (float*)d_out;

    const int* src = ei;
    const int* dst = ei + NE;

    // workspace layout: [zeroed: degi | fillc | sums | cnt] then the rest
    int*   degi   = (int*)d_ws;            // NN
    int*   fillc  = degi + NN;             // NN
    float* sums   = (float*)(fillc + NN);  // NG*H
    float* cnt    = sums + NG * H;         // NG
    int*   bsum   = (int*)(cnt + NG);      // SCAN_NB
    int*   rowptr = bsum + SCAN_NB;        // NN+1
    int*   csr_s  = rowptr + NN + 1;       // NE
    float* csr_w  = (float*)(csr_s + NE);  // NE
    float* dinv   = csr_w + NE;            // NN
    float* tbuf   = dinv + NN;             // NN*H
    float* hA     = tbuf + (long long)NN * H;
    float* hB     = hA + (long long)NN * H;

    const int B = 256;
    const int gE  = (NE + B - 1) / B;
    const int gNH = (NN * H + B - 1) / B;   // one wave per node

    size_t zbytes = (size_t)(NN + NN + NG * H + NG) * 4;
    hipMemsetAsync(d_ws, 0, zbytes, stream);

    // CSR + norm
    k_degi<<<gE, B, 0, stream>>>(dst, degi);
    k_scanA<<<SCAN_NB, SCAN_B, 0, stream>>>(degi, rowptr, bsum);
    k_scanB<<<1, 64, 0, stream>>>(bsum);
    k_scanC<<<SCAN_NB, SCAN_B, 0, stream>>>(bsum, rowptr, degi, dinv);
    k_fill<<<gE, B, 0, stream>>>(src, dst, rowptr, dinv, fillc, csr_s, csr_w);

    // conv1
    k_gemm<4, false><<<gNH, B, 0, stream>>>(x, W1, tbuf);
    k_conv<<<gNH, B, 0, stream>>>(tbuf, rowptr, csr_s, csr_w, dinv, b1, hA);
    // conv2
    k_gemm<H, true><<<gNH, B, 0, stream>>>(hA, W2, tbuf);
    k_conv<<<gNH, B, 0, stream>>>(tbuf, rowptr, csr_s, csr_w, dinv, b2, hB);
    // conv3
    k_gemm<H, true><<<gNH, B, 0, stream>>>(hB, W3, tbuf);
    k_conv<<<gNH, B, 0, stream>>>(tbuf, rowptr, csr_s, csr_w, dinv, b3, hA);

    // pool + head
    k_pool<<<POOL_WAVES / 4, B, 0, stream>>>(hA, batch, sums, cnt);
    k_head<<<1, B, 0, stream>>>(sums, cnt, Wpre, bpre, Wlin, blin, out);
}

// Round 4
// 311.918 us; speedup vs baseline: 3.5634x; 1.1554x over previous
//
#include <hip/hip_runtime.h>

constexpr int NN = 50000;   // nodes
constexpr int NE = 800000;  // edges
constexpr int H  = 64;      // hidden
constexpr int NG = 64;      // graphs

constexpr int SCAN_B  = 1024;
constexpr int SCAN_NB = (NN + SCAN_B - 1) / SCAN_B;  // 49

// ---------------- CSR build ----------------
__global__ void k_degi(const int* __restrict__ dst, int* __restrict__ degi) {
    int e = blockIdx.x * blockDim.x + threadIdx.x;
    if (e < NE) atomicAdd(&degi[dst[e]], 1);
}

// per-block local exclusive scan; bsum[b] = block total
__global__ void k_scanA(const int* __restrict__ degi, int* __restrict__ rowptr,
                        int* __restrict__ bsum) {
    int tid = threadIdx.x, b = blockIdx.x;
    int i = b * SCAN_B + tid;
    int d = (i < NN) ? degi[i] : 0;
    int lane = tid & 63, w = tid >> 6;
    int v = d;
    for (int off = 1; off < 64; off <<= 1) {
        int u = __shfl_up(v, off);
        if (lane >= off) v += u;
    }
    __shared__ int wt[16], wo[16];
    if (lane == 63) wt[w] = v;
    __syncthreads();
    if (tid == 0) {
        int a = 0;
        for (int k = 0; k < 16; ++k) { wo[k] = a; a += wt[k]; }
        bsum[b] = a;
    }
    __syncthreads();
    if (i < NN) rowptr[i] = v - d + wo[w];
}

// single wave: bsum -> exclusive offsets (in place)
__global__ void k_scanB(int* __restrict__ bsum) {
    int lane = threadIdx.x;
    int v = (lane < SCAN_NB) ? bsum[lane] : 0;
    int s = v;
    for (int off = 1; off < 64; off <<= 1) {
        int u = __shfl_up(s, off);
        if (lane >= off) s += u;
    }
    if (lane < SCAN_NB) bsum[lane] = s - v;
}

// add block offsets; fuse dinv
__global__ void k_scanC(const int* __restrict__ bsum, int* __restrict__ rowptr,
                        const int* __restrict__ degi, float* __restrict__ dinv) {
    int i = blockIdx.x * SCAN_B + threadIdx.x;
    if (i < NN) {
        rowptr[i] += bsum[blockIdx.x];
        dinv[i] = rsqrtf((float)(degi[i] + 1));  // +1 self-loop
    }
    if (i == 0) rowptr[NN] = NE;
}

__global__ void k_fill(const int* __restrict__ src, const int* __restrict__ dst,
                       const int* __restrict__ rowptr, const float* __restrict__ dinv,
                       int* __restrict__ fillc, int* __restrict__ csr_src,
                       float* __restrict__ csr_w) {
    int e = blockIdx.x * blockDim.x + threadIdx.x;
    if (e >= NE) return;
    int s = src[e], d = dst[e];
    int pos = rowptr[d] + atomicAdd(&fillc[d], 1);
    csr_src[pos] = s;
    csr_w[pos] = dinv[s] * dinv[d];
}

// ---------------- dense per-node GEMM: t = act(h) @ W ----------------
// block = 256 threads; each thread computes a 4-row x 4-channel micro-tile.
// Block tile: 64 rows x 64 channels. W (K x 64) staged in LDS as float4.
template <int K, bool RELU>
__global__ void k_gemm(const float* __restrict__ h, const float* __restrict__ W,
                       float* __restrict__ t) {
    __shared__ float4 Wl[K][16];
    int tid = threadIdx.x;
    {
        const float4* W4 = (const float4*)W;
        for (int i = tid; i < K * 16; i += 256) ((float4*)Wl)[i] = W4[i];
    }
    __syncthreads();
    int cg = tid & 15;   // channel group: channels 4*cg..4*cg+3
    int rg = tid >> 4;   // row group: 4 consecutive rows
    int row0 = blockIdx.x * 64 + rg * 4;

    float4 acc[4];
#pragma unroll
    for (int i = 0; i < 4; ++i) acc[i] = make_float4(0.f, 0.f, 0.f, 0.f);

    const float4* h4 = (const float4*)h;   // h4[r*(K/4) + k4]
#pragma unroll
    for (int k4 = 0; k4 < K / 4; ++k4) {
        float4 w0 = Wl[4 * k4 + 0][cg];
        float4 w1 = Wl[4 * k4 + 1][cg];
        float4 w2 = Wl[4 * k4 + 2][cg];
        float4 w3 = Wl[4 * k4 + 3][cg];
#pragma unroll
        for (int i = 0; i < 4; ++i) {
            int r = row0 + i;
            if (r >= NN) break;
            float4 hv = h4[(long long)r * (K / 4) + k4];
            if (RELU) {
                hv.x = fmaxf(hv.x, 0.f); hv.y = fmaxf(hv.y, 0.f);
                hv.z = fmaxf(hv.z, 0.f); hv.w = fmaxf(hv.w, 0.f);
            }
            acc[i].x = fmaf(hv.x, w0.x, acc[i].x);
            acc[i].y = fmaf(hv.x, w0.y, acc[i].y);
            acc[i].z = fmaf(hv.x, w0.z, acc[i].z);
            acc[i].w = fmaf(hv.x, w0.w, acc[i].w);
            acc[i].x = fmaf(hv.y, w1.x, acc[i].x);
            acc[i].y = fmaf(hv.y, w1.y, acc[i].y);
            acc[i].z = fmaf(hv.y, w1.z, acc[i].z);
            acc[i].w = fmaf(hv.y, w1.w, acc[i].w);
            acc[i].x = fmaf(hv.z, w2.x, acc[i].x);
            acc[i].y = fmaf(hv.z, w2.y, acc[i].y);
            acc[i].z = fmaf(hv.z, w2.z, acc[i].z);
            acc[i].w = fmaf(hv.z, w2.w, acc[i].w);
            acc[i].x = fmaf(hv.w, w3.x, acc[i].x);
            acc[i].y = fmaf(hv.w, w3.y, acc[i].y);
            acc[i].z = fmaf(hv.w, w3.z, acc[i].z);
            acc[i].w = fmaf(hv.w, w3.w, acc[i].w);
        }
    }
#pragma unroll
    for (int i = 0; i < 4; ++i) {
        int r = row0 + i;
        if (r < NN) *(float4*)(t + (long long)r * H + 4 * cg) = acc[i];
    }
}

// ---------------- pull conv, float4 / 4-edges-per-pass ----------------
// wave = 1 dst node; lane = (g = lane>>4 edge group, l = lane&15 float4 slot)
__global__ void k_conv(const float* __restrict__ t, const int* __restrict__ rowptr,
                       const int* __restrict__ csr_src, const float* __restrict__ csr_w,
                       const float* __restrict__ dinv, const float* __restrict__ b,
                       float* __restrict__ out) {
    int wid = (blockIdx.x * blockDim.x + threadIdx.x) >> 6;
    int lane = threadIdx.x & 63;
    int l = lane & 15, g = lane >> 4;
    if (wid >= NN) return;
    float ax = 0.0f, ay = 0.0f, az = 0.0f, aw = 0.0f;
    int beg = rowptr[wid], end = rowptr[wid + 1];
    for (int base = beg; base < end; base += 64) {
        int k = base + lane;
        int s = 0; float w = 0.0f;
        if (k < end) { s = csr_src[k]; w = csr_w[k]; }
        int n = end - base; if (n > 64) n = 64;
        int iters = (n + 3) >> 2;
        for (int j = 0; j < iters; ++j) {
            int idx = 4 * j + g;
            int ss = __shfl(s, idx);
            float ww = __shfl(w, idx);
            const float4 v = *(const float4*)(t + (long long)ss * H + 4 * l);
            ax = fmaf(v.x, ww, ax);
            ay = fmaf(v.y, ww, ay);
            az = fmaf(v.z, ww, az);
            aw = fmaf(v.w, ww, aw);
        }
    }
    ax += __shfl_xor(ax, 16); ax += __shfl_xor(ax, 32);
    ay += __shfl_xor(ay, 16); ay += __shfl_xor(ay, 32);
    az += __shfl_xor(az, 16); az += __shfl_xor(az, 32);
    aw += __shfl_xor(aw, 16); aw += __shfl_xor(aw, 32);
    if (g == 0) {
        float dd = dinv[wid];
        float s2 = dd * dd;
        const float4 sv = *(const float4*)(t + (long long)wid * H + 4 * l);
        const float4 bv = *(const float4*)(b + 4 * l);
        float4 o;
        o.x = ax + bv.x + sv.x * s2;
        o.y = ay + bv.y + sv.y * s2;
        o.z = az + bv.z + sv.z * s2;
        o.w = aw + bv.w + sv.w * s2;
        *(float4*)(out + (long long)wid * H + 4 * l) = o;
    }
}

// ---------------- pooling: run-length segmented reduction (batch sorted) ----------------
constexpr int POOL_WAVES = 512;
constexpr int POOL_STRIP = (NN + POOL_WAVES - 1) / POOL_WAVES;  // 98

__global__ void k_pool(const float* __restrict__ h, const int* __restrict__ batch,
                       float* __restrict__ sums, float* __restrict__ cnt) {
    int wid = (blockIdx.x * blockDim.x + threadIdx.x) >> 6;
    int c = threadIdx.x & 63;
    int beg = wid * POOL_STRIP, end = min(NN, beg + POOL_STRIP);
    if (beg >= end) return;
    int curg = batch[beg];
    float acc = 0.0f; int run = 0;
    for (int r = beg; r < end; ++r) {
        int g = batch[r];
        if (g != curg) {
            atomicAdd(&sums[curg * H + c], acc);
            if (c == 0) atomicAdd(&cnt[curg], (float)run);
            curg = g; acc = 0.0f; run = 0;
        }
        acc += h[(long long)r * H + c];
        ++run;
    }
    atomicAdd(&sums[curg * H + c], acc);
    if (c == 0) atomicAdd(&cnt[curg], (float)run);
}

// ---------------- head ----------------
__global__ void k_head(const float* __restrict__ sums, const float* __restrict__ cnt,
                       const float* __restrict__ Wpre, const float* __restrict__ bpre,
                       const float* __restrict__ Wlin, const float* __restrict__ blin,
                       float* __restrict__ out) {
    __shared__ float g[NG * H];
    __shared__ float p[NG * 32];
    int tid = threadIdx.x;
    for (int i = tid; i < NG * H; i += blockDim.x) {
        int gi = i >> 6;
        g[i] = sums[i] / fmaxf(cnt[gi], 1.0f);
    }
    __syncthreads();
    for (int i = tid; i < NG * 32; i += blockDim.x) {
        int gi = i >> 5, j = i & 31;
        float acc = bpre[j];
        for (int k = 0; k < H; ++k) acc = fmaf(g[gi * H + k], Wpre[k * 32 + j], acc);
        p[i] = acc;
    }
    __syncthreads();
    for (int i = tid; i < NG * 4; i += blockDim.x) {
        int gi = i >> 2, o = i & 3;
        float acc = blin[o];
        for (int j = 0; j < 32; ++j) acc = fmaf(p[gi * 32 + j], Wlin[j * 4 + o], acc);
        out[i] = acc;
    }
}

extern "C" void kernel_launch(void* const* d_in, const int* in_sizes, int n_in,
                              void* d_out, int out_size, void* d_ws, size_t ws_size,
                              hipStream_t stream) {
    const float* x     = (const float*)d_in[0];
    const int*   ei    = (const int*)d_in[1];
    const int*   batch = (const int*)d_in[2];
    const float* W1    = (const float*)d_in[3];
    const float* b1    = (const float*)d_in[4];
    const float* W2    = (const float*)d_in[5];
    const float* b2    = (const float*)d_in[6];
    const float* W3    = (const float*)d_in[7];
    const float* b3    = (const float*)d_in[8];
    const float* Wpre  = (const float*)d_in[9];
    const float* bpre  = (const float*)d_in[10];
    const float* Wlin  = (const float*)d_in[11];
    const float* blin  = (const float*)d_in[12];
    float* out = (float*)d_out;

    const int* src = ei;
    const int* dst = ei + NE;

    // workspace layout: [zeroed: degi | fillc | sums | cnt] then the rest
    int*   degi   = (int*)d_ws;            // NN
    int*   fillc  = degi + NN;             // NN
    float* sums   = (float*)(fillc + NN);  // NG*H
    float* cnt    = sums + NG * H;         // NG
    int*   bsum   = (int*)(cnt + NG);      // SCAN_NB
    int*   rowptr = bsum + SCAN_NB;        // NN+1
    int*   csr_s  = rowptr + NN + 1;       // NE
    float* csr_w  = (float*)(csr_s + NE);  // NE
    float* dinv   = csr_w + NE;            // NN
    float* tbuf   = dinv + NN;             // NN*H
    float* hA     = tbuf + (long long)NN * H;
    float* hB     = hA + (long long)NN * H;

    const int B = 256;
    const int gE  = (NE + B - 1) / B;
    const int gNH = (NN * H + B - 1) / B;     // one wave per node (conv)
    const int gG  = (NN + 63) / 64;           // gemm: 64 rows per block

    size_t zbytes = (size_t)(NN + NN + NG * H + NG) * 4;
    hipMemsetAsync(d_ws, 0, zbytes, stream);

    // CSR + norm
    k_degi<<<gE, B, 0, stream>>>(dst, degi);
    k_scanA<<<SCAN_NB, SCAN_B, 0, stream>>>(degi, rowptr, bsum);
    k_scanB<<<1, 64, 0, stream>>>(bsum);
    k_scanC<<<SCAN_NB, SCAN_B, 0, stream>>>(bsum, rowptr, degi, dinv);
    k_fill<<<gE, B, 0, stream>>>(src, dst, rowptr, dinv, fillc, csr_s, csr_w);

    // conv1
    k_gemm<4, false><<<gG, B, 0, stream>>>(x, W1, tbuf);
    k_conv<<<gNH, B, 0, stream>>>(tbuf, rowptr, csr_s, csr_w, dinv, b1, hA);
    // conv2
    k_gemm<H, true><<<gG, B, 0, stream>>>(hA, W2, tbuf);
    k_conv<<<gNH, B, 0, stream>>>(tbuf, rowptr, csr_s, csr_w, dinv, b2, hB);
    // conv3
    k_gemm<H, true><<<gG, B, 0, stream>>>(hB, W3, tbuf);
    k_conv<<<gNH, B, 0, stream>>>(tbuf, rowptr, csr_s, csr_w, dinv, b3, hA);

    // pool + head
    k_pool<<<POOL_WAVES / 4, B, 0, stream>>>(hA, batch, sums, cnt);
    k_head<<<1, B, 0, stream>>>(sums, cnt, Wpre, bpre, Wlin, blin, out);
}